// Round 5
// baseline (48.625 us; speedup 1.0000x reference)
//
#include <hip/hip_runtime.h>

// 3x3 median, replicate border, float32, 8 x 2048 x 2048.
// Each thread: 4-wide x 16-tall column strip. 18 row-loads feed a 3-slot
// sorted-triple ring (lo, md, hi); 16 outputs via
//   median9 = med3( max3(lo0,lo1,lo2), med3(md0,md1,md2), min3(hi0,hi1,hi2) )
// R5: explicit 6-deep load prefetch ring for memory-level parallelism —
// R4 had VGPR=36 (compiler kept ~2 loads in flight) and HBM at only 4.4 of
// 6.3 TB/s => latency-bound. Halo via wave shuffles; nt stores.

#define MIN3(a,b,c) fminf(fminf((a),(b)),(c))
#define MAX3(a,b,c) fmaxf(fmaxf((a),(b)),(c))
#define MED3(a,b,c) __builtin_amdgcn_fmed3f((a),(b),(c))

typedef float nfloat4 __attribute__((ext_vector_type(4)));

constexpr int W  = 2048;
constexpr int H  = 2048;
constexpr int W4 = W / 4;        // 512
constexpr int R  = 16;           // output rows per thread
constexpr int TY = H / R;        // 128 tiles vertically
constexpr int PF = 6;            // prefetch depth (loads in flight)

__global__ __launch_bounds__(256) void median3x3_kernel(
    const float* __restrict__ in, float* __restrict__ out, int nblocks) {
    // Bijective XCD-aware chunked swizzle (nblocks % 8 == 0): each XCD gets a
    // contiguous work chunk -> vertical halo rows reused within one L2.
    int b   = blockIdx.x;
    int cpx = nblocks >> 3;
    int swz = (b & 7) * cpx + (b >> 3);
    int idx = swz * 256 + (int)threadIdx.x;

    int x4    = idx & (W4 - 1);          // 9 bits
    int yt    = (idx >> 9) & (TY - 1);   // 7 bits
    int img_i = idx >> 16;               // [0, 8)

    const float* img  = in  + (size_t)img_i * H * W;
    float*       oimg = out + (size_t)img_i * H * W;

    int lane = (int)threadIdx.x & 63;
    int x    = x4 << 2;
    int y0   = yt * R;

    // prefetch ring: issue PF row-loads before consuming any
    nfloat4 v[PF];
    #pragma unroll
    for (int i = 0; i < PF; ++i) {
        int yi = max(0, min(H - 1, y0 - 1 + i));
        v[i] = *reinterpret_cast<const nfloat4*>(img + (size_t)yi * W + x);
    }

    float lo[3][4], md[3][4], hi[3][4];

    #pragma unroll
    for (int i = 0; i < R + 2; ++i) {
        int yi = max(0, min(H - 1, y0 - 1 + i));
        const float* row = img + (size_t)yi * W;

        nfloat4 cur = v[i % PF];                 // waits only on oldest load
        if (i + PF < R + 2) {                    // refill slot with row i+PF
            int yn = max(0, min(H - 1, y0 - 1 + i + PF));
            v[i % PF] =
                *reinterpret_cast<const nfloat4*>(img + (size_t)yn * W + x);
        }

        // horizontal halo from neighbor lanes; fix wave-boundary lanes
        float e0 = __shfl_up(cur.w, 1);
        float e5 = __shfl_down(cur.x, 1);
        if (lane == 0)  e0 = (x4 == 0)      ? cur.x : row[x - 1];
        if (lane == 63) e5 = (x4 == W4 - 1) ? cur.w : row[x + 4];

        float e[6] = { e0, cur.x, cur.y, cur.z, cur.w, e5 };
        const int s = i % 3;   // compile-time constant after full unroll
        #pragma unroll
        for (int j = 0; j < 4; ++j) {
            float a = e[j], bb = e[j + 1], c = e[j + 2];
            lo[s][j] = MIN3(a, bb, c);
            md[s][j] = MED3(a, bb, c);
            hi[s][j] = MAX3(a, bb, c);
        }

        if (i >= 2) {
            nfloat4 o;
            #pragma unroll
            for (int j = 0; j < 4; ++j) {
                float mx = MAX3(lo[0][j], lo[1][j], lo[2][j]);
                float me = MED3(md[0][j], md[1][j], md[2][j]);
                float mn = MIN3(hi[0][j], hi[1][j], hi[2][j]);
                o[j] = MED3(mx, me, mn);   // row-permutation invariant
            }
            __builtin_nontemporal_store(
                o, reinterpret_cast<nfloat4*>(oimg + (size_t)(y0 + i - 2) * W + x));
        }
    }
}

extern "C" void kernel_launch(void* const* d_in, const int* in_sizes, int n_in,
                              void* d_out, int out_size, void* d_ws, size_t ws_size,
                              hipStream_t stream) {
    const float* x = (const float*)d_in[0];
    float* outp = (float*)d_out;

    int B = in_sizes[0] / (H * W);                 // 8
    int total = B * TY * W4;                       // 524,288 threads
    int block = 256;
    int grid  = total / block;                     // 2048 blocks (% 8 == 0)

    median3x3_kernel<<<grid, block, 0, stream>>>(x, outp, grid);
}

// Round 6
// 45.110 us; speedup vs baseline: 1.0779x; 1.0779x over previous
//
#include <hip/hip_runtime.h>

// 3x3 median, replicate border, float32, 8 x 2048 x 2048.
// Each thread: 4-wide x 32-tall column strip. 34 row-loads feed a 3-slot
// sorted-triple ring (lo, md, hi); 32 outputs via
//   median9 = med3( max3(lo0,lo1,lo2), med3(md0,md1,md2), min3(hi0,hi1,hi2) )
// R6: reverted R5's explicit prefetch ring (FAILED: VGPR 48, occupancy -15pt,
// +1.8us — compiler-scheduled loads in the unrolled loop already give enough
// MLP). R=16 -> 32 cuts vertical read amplification 1.125x -> 1.0625x.
// Halo via wave shuffles (lanes 0/63 masked scalar fixups); nt stores keep
// the write stream out of L2/L3 so the input stays cache-resident.

#define MIN3(a,b,c) fminf(fminf((a),(b)),(c))
#define MAX3(a,b,c) fmaxf(fmaxf((a),(b)),(c))
#define MED3(a,b,c) __builtin_amdgcn_fmed3f((a),(b),(c))

typedef float nfloat4 __attribute__((ext_vector_type(4)));

constexpr int W  = 2048;
constexpr int H  = 2048;
constexpr int W4 = W / 4;        // 512
constexpr int R  = 32;           // output rows per thread
constexpr int TY = H / R;        // 64 tiles vertically

__global__ __launch_bounds__(256) void median3x3_kernel(
    const float* __restrict__ in, float* __restrict__ out, int nblocks) {
    // Bijective XCD-aware chunked swizzle (nblocks % 8 == 0): each XCD gets a
    // contiguous work chunk -> vertical halo rows reused within one L2.
    int b   = blockIdx.x;
    int cpx = nblocks >> 3;
    int swz = (b & 7) * cpx + (b >> 3);
    int idx = swz * 256 + (int)threadIdx.x;

    int x4    = idx & (W4 - 1);          // 9 bits
    int yt    = (idx >> 9) & (TY - 1);   // 6 bits
    int img_i = idx >> 15;               // [0, 8)

    const float* img  = in  + (size_t)img_i * H * W;
    float*       oimg = out + (size_t)img_i * H * W;

    int lane = (int)threadIdx.x & 63;
    int x    = x4 << 2;
    int y0   = yt * R;

    float lo[3][4], md[3][4], hi[3][4];

    #pragma unroll
    for (int i = 0; i < R + 2; ++i) {
        int yi = max(0, min(H - 1, y0 - 1 + i));
        const float* row = img + (size_t)yi * W;
        nfloat4 v = *reinterpret_cast<const nfloat4*>(row + x);

        // horizontal halo from neighbor lanes; fix wave-boundary lanes
        float e0 = __shfl_up(v.w, 1);
        float e5 = __shfl_down(v.x, 1);
        if (lane == 0)  e0 = (x4 == 0)      ? v.x : row[x - 1];
        if (lane == 63) e5 = (x4 == W4 - 1) ? v.w : row[x + 4];

        float e[6] = { e0, v.x, v.y, v.z, v.w, e5 };
        const int s = i % 3;   // compile-time constant after full unroll
        #pragma unroll
        for (int j = 0; j < 4; ++j) {
            float a = e[j], bb = e[j + 1], c = e[j + 2];
            lo[s][j] = MIN3(a, bb, c);
            md[s][j] = MED3(a, bb, c);
            hi[s][j] = MAX3(a, bb, c);
        }

        if (i >= 2) {
            nfloat4 o;
            #pragma unroll
            for (int j = 0; j < 4; ++j) {
                float mx = MAX3(lo[0][j], lo[1][j], lo[2][j]);
                float me = MED3(md[0][j], md[1][j], md[2][j]);
                float mn = MIN3(hi[0][j], hi[1][j], hi[2][j]);
                o[j] = MED3(mx, me, mn);   // row-permutation invariant
            }
            __builtin_nontemporal_store(
                o, reinterpret_cast<nfloat4*>(oimg + (size_t)(y0 + i - 2) * W + x));
        }
    }
}

extern "C" void kernel_launch(void* const* d_in, const int* in_sizes, int n_in,
                              void* d_out, int out_size, void* d_ws, size_t ws_size,
                              hipStream_t stream) {
    const float* x = (const float*)d_in[0];
    float* outp = (float*)d_out;

    int B = in_sizes[0] / (H * W);                 // 8
    int total = B * TY * W4;                       // 262,144 threads
    int block = 256;
    int grid  = total / block;                     // 1024 blocks (% 8 == 0)

    median3x3_kernel<<<grid, block, 0, stream>>>(x, outp, grid);
}

// Round 8
// 45.075 us; speedup vs baseline: 1.0787x; 1.0008x over previous
//
#include <hip/hip_runtime.h>

// 3x3 median, replicate border, float32, 8 x 2048 x 2048.  (R8 = revert to R6)
// Each thread: 4-wide x 32-tall column strip. 34 row-loads feed a 3-slot
// sorted-triple ring (lo, md, hi); 32 outputs via
//   median9 = med3( max3(lo0,lo1,lo2), med3(md0,md1,md2), min3(hi0,hi1,hi2) )
// History: R5 explicit prefetch ring FAILED (latency not the limiter);
// R7 sc0/sc1/nt full cache-bypass stores FAILED CORRECTNESS (stale
// memset/poison lines in L2/MALL shadow bypass writes — unfixable race).
// Builtin nt store (allocate, low-retention) is the best safe write policy.
// Steady state: ~4.4 TB/s aggregate HBM (131MB write + ~70MB read), VALU 11%,
// 0 bank conflicts — mixed-traffic memory roofline.

#define MIN3(a,b,c) fminf(fminf((a),(b)),(c))
#define MAX3(a,b,c) fmaxf(fmaxf((a),(b)),(c))
#define MED3(a,b,c) __builtin_amdgcn_fmed3f((a),(b),(c))

typedef float nfloat4 __attribute__((ext_vector_type(4)));

constexpr int W  = 2048;
constexpr int H  = 2048;
constexpr int W4 = W / 4;        // 512
constexpr int R  = 32;           // output rows per thread
constexpr int TY = H / R;        // 64 tiles vertically

__global__ __launch_bounds__(256) void median3x3_kernel(
    const float* __restrict__ in, float* __restrict__ out, int nblocks) {
    // Bijective XCD-aware chunked swizzle (nblocks % 8 == 0): each XCD gets a
    // contiguous work chunk -> vertical halo rows reused within one L2.
    int b   = blockIdx.x;
    int cpx = nblocks >> 3;
    int swz = (b & 7) * cpx + (b >> 3);
    int idx = swz * 256 + (int)threadIdx.x;

    int x4    = idx & (W4 - 1);          // 9 bits
    int yt    = (idx >> 9) & (TY - 1);   // 6 bits
    int img_i = idx >> 15;               // [0, 8)

    const float* img  = in  + (size_t)img_i * H * W;
    float*       oimg = out + (size_t)img_i * H * W;

    int lane = (int)threadIdx.x & 63;
    int x    = x4 << 2;
    int y0   = yt * R;

    float lo[3][4], md[3][4], hi[3][4];

    #pragma unroll
    for (int i = 0; i < R + 2; ++i) {
        int yi = max(0, min(H - 1, y0 - 1 + i));
        const float* row = img + (size_t)yi * W;
        nfloat4 v = *reinterpret_cast<const nfloat4*>(row + x);

        // horizontal halo from neighbor lanes; fix wave-boundary lanes
        float e0 = __shfl_up(v.w, 1);
        float e5 = __shfl_down(v.x, 1);
        if (lane == 0)  e0 = (x4 == 0)      ? v.x : row[x - 1];
        if (lane == 63) e5 = (x4 == W4 - 1) ? v.w : row[x + 4];

        float e[6] = { e0, v.x, v.y, v.z, v.w, e5 };
        const int s = i % 3;   // compile-time constant after full unroll
        #pragma unroll
        for (int j = 0; j < 4; ++j) {
            float a = e[j], bb = e[j + 1], c = e[j + 2];
            lo[s][j] = MIN3(a, bb, c);
            md[s][j] = MED3(a, bb, c);
            hi[s][j] = MAX3(a, bb, c);
        }

        if (i >= 2) {
            nfloat4 o;
            #pragma unroll
            for (int j = 0; j < 4; ++j) {
                float mx = MAX3(lo[0][j], lo[1][j], lo[2][j]);
                float me = MED3(md[0][j], md[1][j], md[2][j]);
                float mn = MIN3(hi[0][j], hi[1][j], hi[2][j]);
                o[j] = MED3(mx, me, mn);   // row-permutation invariant
            }
            __builtin_nontemporal_store(
                o, reinterpret_cast<nfloat4*>(oimg + (size_t)(y0 + i - 2) * W + x));
        }
    }
}

extern "C" void kernel_launch(void* const* d_in, const int* in_sizes, int n_in,
                              void* d_out, int out_size, void* d_ws, size_t ws_size,
                              hipStream_t stream) {
    const float* x = (const float*)d_in[0];
    float* outp = (float*)d_out;

    int B = in_sizes[0] / (H * W);                 // 8
    int total = B * TY * W4;                       // 262,144 threads
    int block = 256;
    int grid  = total / block;                     // 1024 blocks (% 8 == 0)

    median3x3_kernel<<<grid, block, 0, stream>>>(x, outp, grid);
}